// Round 2
// baseline (273.588 us; speedup 1.0000x reference)
//
#include <hip/hip_runtime.h>
#include <hip/hip_cooperative_groups.h>

namespace cg = cooperative_groups;

#define HDIM 4096
#define NIN 17
#define NA 4

// ---- config ----
constexpr int TB = 256;                 // threads per block
constexpr int CPT = 4;                  // columns per thread (one float4)
constexpr int BXC = HDIM / (TB * CPT);  // 4 column groups
constexpr int NCHUNK = 256;             // row chunks
constexpr int RPC = HDIM / NCHUNK;      // 16 rows per chunk
constexpr size_t NELEM = (size_t)HDIM * HDIM;

// ============================================================================
// Fused cooperative kernel.
// Grid (4,256) = 1024 blocks = exactly 4 blocks/CU (256 CUs) at <=128 VGPR.
// Phase 1: partial matvec; hebb tile (16 x float4 = 64 VGPR) retained.
// Phase 2: grid-wide reduce -> h = tanh(i2h + matvec).
// Phase 3: hebb_new from register-held hebb (no re-read); block 1023 does heads.
// ============================================================================
__global__ __launch_bounds__(TB, 4)
void k_fused(const float* __restrict__ w, const float* __restrict__ alpha,
             const float* __restrict__ hebb, const float* __restrict__ hidden,
             const float* __restrict__ x, const float* __restrict__ i2h_w,
             const float* __restrict__ i2h_b,
             const float* __restrict__ h2o_w, const float* __restrict__ h2o_b,
             const float* __restrict__ h2v_w, const float* __restrict__ h2v_b,
             const float* __restrict__ eta,
             float* __restrict__ partial, float* __restrict__ h_f,
             float* __restrict__ out) {
    const int tid = threadIdx.x;
    const int bx = blockIdx.x;            // 0..3   column group
    const int by = blockIdx.y;            // 0..255 row chunk
    const int col0 = (bx * TB + tid) * CPT;
    const int row0 = by * RPC;

    __shared__ float4 red4[TB];           // 4 KB
    __shared__ float redh[TB];            // 1 KB (heads block only)

    // ---------------- phase 1: partial matvec, retain hebb in regs ----------
    const size_t base = (size_t)row0 * HDIM + col0;
    const float* wp = w + base;
    const float* ap = alpha + base;
    const float* bp = hebb + base;

    float4 hb[RPC];
#pragma unroll
    for (int r = 0; r < RPC; ++r)         // burst: 16 loads in flight at once
        hb[r] = *(const float4*)(bp + (size_t)r * HDIM);

    float4 wv[2], av[2];
    wv[0] = *(const float4*)(wp);
    av[0] = *(const float4*)(ap);
    float4 acc = make_float4(0.f, 0.f, 0.f, 0.f);
#pragma unroll
    for (int r = 0; r < RPC; ++r) {
        if (r + 1 < RPC) {                // 2-deep explicit pipeline for w/alpha
            wv[(r + 1) & 1] = *(const float4*)(wp + (size_t)(r + 1) * HDIM);
            av[(r + 1) & 1] = *(const float4*)(ap + (size_t)(r + 1) * HDIM);
        }
        const float hv = hidden[row0 + r];
        const float4 wv0 = wv[r & 1], av0 = av[r & 1], bv0 = hb[r];
        acc.x += hv * (wv0.x + av0.x * bv0.x);
        acc.y += hv * (wv0.y + av0.y * bv0.y);
        acc.z += hv * (wv0.z + av0.z * bv0.z);
        acc.w += hv * (wv0.w + av0.w * bv0.w);
    }
    *(float4*)(partial + (size_t)by * HDIM + col0) = acc;

    cg::this_grid().sync();

    // ---------------- phase 2: reduce partials -> h -------------------------
    // Each of the 1024 blocks owns 4 columns; thread t reduces chunk t.
    const int flat = by * BXC + bx;       // 0..1023
    const int j0 = flat * 4;
    red4[tid] = *(const float4*)(partial + (size_t)tid * HDIM + j0);
    __syncthreads();
    for (int s = 128; s > 0; s >>= 1) {
        if (tid < s) {
            float4 m = red4[tid], o = red4[tid + s];
            m.x += o.x; m.y += o.y; m.z += o.z; m.w += o.w;
            red4[tid] = m;
        }
        __syncthreads();
    }
    if (tid < 4) {
        const int j = j0 + tid;
        float z = ((const float*)red4)[tid] + i2h_b[j];
#pragma unroll
        for (int k = 0; k < NIN; ++k) z += x[k] * i2h_w[j * NIN + k];
        const float h = tanhf(z);
        h_f[j] = h;
        out[5 + j] = h;
    }

    cg::this_grid().sync();

    // ---------------- phase 3a: heads (one block, overlaps 3b) --------------
    if (flat == BXC * NCHUNK - 1) {
        float a5[NA + 1] = {0.f, 0.f, 0.f, 0.f, 0.f};
        for (int t = tid; t < HDIM; t += TB) {
            const float hv = h_f[t];
#pragma unroll
            for (int a = 0; a < NA; ++a) a5[a] += hv * h2o_w[(size_t)a * HDIM + t];
            a5[NA] += hv * h2v_w[t];
        }
        float res[NA + 1];
#pragma unroll
        for (int a = 0; a <= NA; ++a) {
            redh[tid] = a5[a];
            __syncthreads();
            for (int s = 128; s > 0; s >>= 1) {
                if (tid < s) redh[tid] += redh[tid + s];
                __syncthreads();
            }
            if (tid == 0) res[a] = redh[0];
            __syncthreads();
        }
        if (tid == 0) {
            float o[NA];
            float mx = -1e30f;
#pragma unroll
            for (int a = 0; a < NA; ++a) { o[a] = res[a] + h2o_b[a]; mx = fmaxf(mx, o[a]); }
            float se = 0.f;
#pragma unroll
            for (int a = 0; a < NA; ++a) { o[a] = __expf(o[a] - mx); se += o[a]; }
#pragma unroll
            for (int a = 0; a < NA; ++a) out[a] = o[a] / se;
            out[NA] = res[NA] + h2v_b[0];
        }
    }

    // ---------------- phase 3b: hebb_new from register-held hebb ------------
    const float e = eta[0];
    const float om = 1.f - e;
    const float4 hvv = *(const float4*)(h_f + col0);  // h for this thread's 4 cols
    float* hebb_out = out + 5 + HDIM;                 // element offset 4101 (4B-aligned)
#pragma unroll
    for (int r = 0; r < RPC; ++r) {
        const float hi = e * hidden[row0 + r];
        const size_t m = (size_t)(row0 + r) * HDIM + col0;
        const float4 b = hb[r];
        hebb_out[m]     = om * b.x + hi * hvv.x;
        hebb_out[m + 1] = om * b.y + hi * hvv.y;
        hebb_out[m + 2] = om * b.z + hi * hvv.z;
        hebb_out[m + 3] = om * b.w + hi * hvv.w;
    }
}

// ============================================================================
// Fallback path (previous 4-kernel version) — used if co-residency check fails.
// ============================================================================
__global__ __launch_bounds__(TB, 4)
void k_matvec(const float* __restrict__ w, const float* __restrict__ alpha,
              const float* __restrict__ hebb, const float* __restrict__ hidden,
              float* __restrict__ partial, float* __restrict__ acc5) {
    if (blockIdx.x == 0 && blockIdx.y == 0 && threadIdx.x < 8) acc5[threadIdx.x] = 0.f;
    const int col0 = (blockIdx.x * TB + threadIdx.x) * CPT;
    const int row0 = blockIdx.y * RPC;
    const size_t base = (size_t)row0 * HDIM + col0;
    const float* wp = w + base;
    const float* ap = alpha + base;
    const float* bp = hebb + base;
    float4 acc = make_float4(0.f, 0.f, 0.f, 0.f);
#pragma unroll 8
    for (int r = 0; r < RPC; ++r) {
        const float hv = hidden[row0 + r];
        const size_t off = (size_t)r * HDIM;
        const float4 wv = *(const float4*)(wp + off);
        const float4 av = *(const float4*)(ap + off);
        const float4 bv = *(const float4*)(bp + off);
        acc.x += hv * (wv.x + av.x * bv.x);
        acc.y += hv * (wv.y + av.y * bv.y);
        acc.z += hv * (wv.z + av.z * bv.z);
        acc.w += hv * (wv.w + av.w * bv.w);
    }
    *(float4*)(partial + (size_t)blockIdx.y * HDIM + col0) = acc;
}

__global__ __launch_bounds__(256)
void k_hact(const float* __restrict__ partial, const float* __restrict__ x,
            const float* __restrict__ i2h_w, const float* __restrict__ i2h_b,
            const float* __restrict__ h2o_w, const float* __restrict__ h2v_w,
            float* __restrict__ h_f, float* __restrict__ h_out,
            float* __restrict__ acc5) {
    const int tid = threadIdx.x;
    const int j = blockIdx.x * 256 + tid;
    float s = 0.f;
#pragma unroll 16
    for (int c = 0; c < NCHUNK; ++c) s += partial[(size_t)c * HDIM + j];
    float z = i2h_b[j] + s;
#pragma unroll
    for (int k = 0; k < NIN; ++k) z += x[k] * i2h_w[j * NIN + k];
    const float h = tanhf(z);
    h_f[j] = h;
    h_out[j] = h;
    float d[NA + 1];
#pragma unroll
    for (int a = 0; a < NA; ++a) d[a] = h * h2o_w[(size_t)a * HDIM + j];
    d[NA] = h * h2v_w[j];
    __shared__ float red[256];
#pragma unroll
    for (int a = 0; a < NA + 1; ++a) {
        red[tid] = d[a];
        __syncthreads();
        for (int sft = 128; sft > 0; sft >>= 1) {
            if (tid < sft) red[tid] += red[tid + sft];
            __syncthreads();
        }
        if (tid == 0) atomicAdd(acc5 + a, red[0]);
        __syncthreads();
    }
}

__global__ __launch_bounds__(256)
void k_hebb(const float* __restrict__ hebb, const float* __restrict__ hidden,
            const float* __restrict__ h_f, const float* __restrict__ eta,
            float* __restrict__ hebb_out) {
    const size_t t = (size_t)blockIdx.x * 256 + threadIdx.x;
    const size_t s = 4 * t + 3;
    const float e = eta[0];
    const float om = 1.f - e;
    if (t == 0) {
        const float hv0 = e * hidden[0];
        hebb_out[0] = om * hebb[0] + hv0 * h_f[0];
        hebb_out[1] = om * hebb[1] + hv0 * h_f[1];
        hebb_out[2] = om * hebb[2] + hv0 * h_f[2];
    }
    if (s + 3 < NELEM) {
        const float b0 = hebb[s];
        const float4 bv = *(const float4*)(hebb + s + 1);
        const float b[4] = {b0, bv.x, bv.y, bv.z};
        float v[4];
#pragma unroll
        for (int k = 0; k < 4; ++k) {
            const size_t m = s + (size_t)k;
            const int i = (int)(m >> 12);
            const int jj = (int)(m & (HDIM - 1));
            v[k] = om * b[k] + e * hidden[i] * h_f[jj];
        }
        *(float4*)(hebb_out + s) = make_float4(v[0], v[1], v[2], v[3]);
    } else {
        for (size_t m = s; m < NELEM; ++m) {
            const int i = (int)(m >> 12);
            const int jj = (int)(m & (HDIM - 1));
            hebb_out[m] = om * hebb[m] + e * hidden[i] * h_f[jj];
        }
    }
}

__global__ __launch_bounds__(64)
void k_finish(const float* __restrict__ acc5,
              const float* __restrict__ h2o_b, const float* __restrict__ h2v_b,
              float* __restrict__ out) {
    if (threadIdx.x == 0) {
        float o[NA];
        float mx = -1e30f;
#pragma unroll
        for (int a = 0; a < NA; ++a) { o[a] = acc5[a] + h2o_b[a]; mx = fmaxf(mx, o[a]); }
        float se = 0.f;
#pragma unroll
        for (int a = 0; a < NA; ++a) { o[a] = __expf(o[a] - mx); se += o[a]; }
#pragma unroll
        for (int a = 0; a < NA; ++a) out[a] = o[a] / se;
        out[NA] = acc5[NA] + h2v_b[0];
    }
}

extern "C" void kernel_launch(void* const* d_in, const int* in_sizes, int n_in,
                              void* d_out, int out_size, void* d_ws, size_t ws_size,
                              hipStream_t stream) {
    const float* x      = (const float*)d_in[0];
    const float* hidden = (const float*)d_in[1];
    const float* hebb   = (const float*)d_in[2];
    const float* i2h_w  = (const float*)d_in[3];
    const float* i2h_b  = (const float*)d_in[4];
    const float* w      = (const float*)d_in[5];
    const float* alpha  = (const float*)d_in[6];
    const float* eta    = (const float*)d_in[7];
    const float* h2o_w  = (const float*)d_in[8];
    const float* h2o_b  = (const float*)d_in[9];
    const float* h2v_w  = (const float*)d_in[10];
    const float* h2v_b  = (const float*)d_in[11];
    float* out = (float*)d_out;

    float* partial = (float*)d_ws;                    // NCHUNK*HDIM floats (4 MB)
    float* h_f  = partial + (size_t)NCHUNK * HDIM;    // HDIM floats
    float* acc5 = h_f + HDIM;                         // 8 floats (fallback only)

    float* h_out    = out + 5;
    float* hebb_out = out + 5 + HDIM;

    // One-time co-residency check: need 1024 blocks resident on 256 CUs.
    static int coop = -1;
    if (coop < 0) {
        int maxb = 0;
        hipError_t err = hipOccupancyMaxActiveBlocksPerMultiprocessor(&maxb, k_fused, TB, 0);
        coop = (err == hipSuccess && maxb >= 4) ? 1 : 0;
    }

    if (coop) {
        void* args[] = {(void*)&w, (void*)&alpha, (void*)&hebb, (void*)&hidden,
                        (void*)&x, (void*)&i2h_w, (void*)&i2h_b,
                        (void*)&h2o_w, (void*)&h2o_b, (void*)&h2v_w, (void*)&h2v_b,
                        (void*)&eta, (void*)&partial, (void*)&h_f, (void*)&out};
        hipLaunchCooperativeKernel(k_fused, dim3(BXC, NCHUNK), dim3(TB), args, 0, stream);
    } else {
        k_matvec<<<dim3(BXC, NCHUNK), TB, 0, stream>>>(w, alpha, hebb, hidden, partial, acc5);
        k_hact<<<HDIM / 256, 256, 0, stream>>>(partial, x, i2h_w, i2h_b, h2o_w, h2v_w, h_f, h_out, acc5);
        k_hebb<<<(int)((NELEM / 4) / 256), 256, 0, stream>>>(hebb, hidden, h_f, eta, hebb_out);
        k_finish<<<1, 64, 0, stream>>>(acc5, h2o_b, h2v_b, out);
    }
}

// Round 3
// 255.736 us; speedup vs baseline: 1.0698x; 1.0698x over previous
//
#include <hip/hip_runtime.h>

#define HDIM 4096
#define NIN 17
#define NA 4

using f4 = __attribute__((ext_vector_type(4))) float;

// ---- config ----
constexpr int TB = 256;                 // threads per block
constexpr int CPT = 4;                  // columns per thread (one float4)
constexpr int BXC = HDIM / (TB * CPT);  // 4 column groups
constexpr int NCHUNK = 1024;            // row chunks (4096 blocks total)
constexpr int RPC = HDIM / NCHUNK;      // 4 rows per chunk
constexpr size_t NELEM = (size_t)HDIM * HDIM;

// Kernel A: partial sums of hidden @ (w + alpha*hebb).
// 4096 blocks (16/CU queued) + explicit 12-load burst per thread:
// all loads issued before first use -> ~48 load VGPRs in flight, no
// loop-carried waitcnt. w/alpha are read-once -> nontemporal (keeps hebb
// resident in L3 for k_hebb's re-read).
__global__ void k_matvec(const float* __restrict__ w, const float* __restrict__ alpha,
                         const float* __restrict__ hebb, const float* __restrict__ hidden,
                         float* __restrict__ partial, float* __restrict__ acc5) {
    if (blockIdx.x == 0 && blockIdx.y == 0 && threadIdx.x < 8) acc5[threadIdx.x] = 0.f;
    const int col0 = (blockIdx.x * TB + threadIdx.x) * CPT;
    const int row0 = blockIdx.y * RPC;
    const size_t base = (size_t)row0 * HDIM + col0;

    f4 wv[RPC], av[RPC], bv[RPC];
#pragma unroll
    for (int r = 0; r < RPC; ++r) {
        const size_t off = base + (size_t)r * HDIM;
        wv[r] = __builtin_nontemporal_load((const f4*)(w + off));
        av[r] = __builtin_nontemporal_load((const f4*)(alpha + off));
        bv[r] = *(const f4*)(hebb + off);
    }
    f4 acc = {0.f, 0.f, 0.f, 0.f};
#pragma unroll
    for (int r = 0; r < RPC; ++r) {
        const float hv = hidden[row0 + r];
        acc += hv * (wv[r] + av[r] * bv[r]);
    }
    *(f4*)(partial + (size_t)blockIdx.y * HDIM + col0) = acc;
}

// Kernel B: reduce 1024 partials per column -> h = tanh(i2h + matvec).
// 128 blocks; block owns 32 cols; 8 chunk-groups of 128 rows each; LDS fold;
// heads fused (shfl-reduce + atomicAdd into acc5).
constexpr int HC = 32;                // cols per block
constexpr int HGRP = TB / HC;         // 8 groups
constexpr int HCPG = NCHUNK / HGRP;   // 128 chunks per group

__global__ void k_hact(const float* __restrict__ partial, const float* __restrict__ x,
                       const float* __restrict__ i2h_w, const float* __restrict__ i2h_b,
                       const float* __restrict__ h2o_w, const float* __restrict__ h2v_w,
                       float* __restrict__ h_f, float* __restrict__ h_out,
                       float* __restrict__ acc5) {
    const int tid = threadIdx.x;
    const int lane = tid & (HC - 1);
    const int grp = tid >> 5;
    const int col = blockIdx.x * HC + lane;

    float s = 0.f;
    const float* p = partial + (size_t)(grp * HCPG) * HDIM + col;
#pragma unroll 16
    for (int c = 0; c < HCPG; ++c) s += p[(size_t)c * HDIM];

    __shared__ float red[TB];
    red[tid] = s;
    __syncthreads();
    for (int st = TB / 2; st >= HC; st >>= 1) {
        if (tid < st) red[tid] += red[tid + st];
        __syncthreads();
    }
    if (tid < HC) {
        float z = red[tid] + i2h_b[col];
#pragma unroll
        for (int k = 0; k < NIN; ++k) z += x[k] * i2h_w[col * NIN + k];
        const float h = tanhf(z);
        h_f[col] = h;
        h_out[col] = h;
        float d[NA + 1];
#pragma unroll
        for (int a = 0; a < NA; ++a) d[a] = h * h2o_w[(size_t)a * HDIM + col];
        d[NA] = h * h2v_w[col];
#pragma unroll
        for (int a = 0; a <= NA; ++a) {
            float v = d[a];
#pragma unroll
            for (int sft = 16; sft > 0; sft >>= 1) v += __shfl_down(v, sft, 32);
            if (lane == 0) atomicAdd(acc5 + a, v);
        }
    }
}

// Kernel C: hebb_new = (1-eta)*hebb + eta*outer(hidden, h).
// s = 4t+3 alignment trick (out+4101 base) -> aligned float4 stores;
// nontemporal stores (never re-read).
__global__ void k_hebb(const float* __restrict__ hebb, const float* __restrict__ hidden,
                       const float* __restrict__ h_f, const float* __restrict__ eta,
                       float* __restrict__ hebb_out) {
    const size_t t = (size_t)blockIdx.x * TB + threadIdx.x;
    const size_t s = 4 * t + 3;
    const float e = eta[0];
    const float om = 1.f - e;

    if (t == 0) {  // head elements 0,1,2 (row 0)
        const float hv0 = e * hidden[0];
        hebb_out[0] = om * hebb[0] + hv0 * h_f[0];
        hebb_out[1] = om * hebb[1] + hv0 * h_f[1];
        hebb_out[2] = om * hebb[2] + hv0 * h_f[2];
    }

    if (s + 3 < NELEM) {
        const float b0 = hebb[s];                        // 4B-aligned scalar
        const f4 bv = *(const f4*)(hebb + s + 1);        // 16B-aligned
        const float b[4] = {b0, bv.x, bv.y, bv.z};
        f4 v;
#pragma unroll
        for (int k = 0; k < 4; ++k) {
            const size_t m = s + (size_t)k;
            const int i = (int)(m >> 12);
            const int jj = (int)(m & (HDIM - 1));
            v[k] = om * b[k] + e * hidden[i] * h_f[jj];
        }
        __builtin_nontemporal_store(v, (f4*)(hebb_out + s));  // 16B-aligned
    } else {
        for (size_t m = s; m < NELEM; ++m) {             // tail element N-1
            const int i = (int)(m >> 12);
            const int jj = (int)(m & (HDIM - 1));
            hebb_out[m] = om * hebb[m] + e * hidden[i] * h_f[jj];
        }
    }
}

// Kernel D: tiny finalize — softmax + value head.
__global__ __launch_bounds__(64)
void k_finish(const float* __restrict__ acc5,
              const float* __restrict__ h2o_b, const float* __restrict__ h2v_b,
              float* __restrict__ out) {
    if (threadIdx.x == 0) {
        float o[NA];
        float mx = -1e30f;
#pragma unroll
        for (int a = 0; a < NA; ++a) { o[a] = acc5[a] + h2o_b[a]; mx = fmaxf(mx, o[a]); }
        float se = 0.f;
#pragma unroll
        for (int a = 0; a < NA; ++a) { o[a] = __expf(o[a] - mx); se += o[a]; }
#pragma unroll
        for (int a = 0; a < NA; ++a) out[a] = o[a] / se;
        out[NA] = acc5[NA] + h2v_b[0];
    }
}

extern "C" void kernel_launch(void* const* d_in, const int* in_sizes, int n_in,
                              void* d_out, int out_size, void* d_ws, size_t ws_size,
                              hipStream_t stream) {
    const float* x      = (const float*)d_in[0];
    const float* hidden = (const float*)d_in[1];
    const float* hebb   = (const float*)d_in[2];
    const float* i2h_w  = (const float*)d_in[3];
    const float* i2h_b  = (const float*)d_in[4];
    const float* w      = (const float*)d_in[5];
    const float* alpha  = (const float*)d_in[6];
    const float* eta    = (const float*)d_in[7];
    const float* h2o_w  = (const float*)d_in[8];
    const float* h2o_b  = (const float*)d_in[9];
    const float* h2v_w  = (const float*)d_in[10];
    const float* h2v_b  = (const float*)d_in[11];
    float* out = (float*)d_out;

    // out layout: activout[4] | valueout[1] | h[4096] | hebb_new[4096*4096]
    float* h_out    = out + 5;
    float* hebb_out = out + 5 + HDIM;

    // partial[NCHUNK][HDIM] (16 MB) lives in the hebb_out region as scratch:
    // consumed by k_hact, then fully overwritten by k_hebb. Offset 8192 floats
    // keeps it 16B-aligned and clear of activout/value/h (first 4101 floats).
    float* partial = out + 8192;

    float* h_f  = (float*)d_ws;        // HDIM floats
    float* acc5 = h_f + HDIM;          // 8 floats (5 used)

    k_matvec<<<dim3(BXC, NCHUNK), TB, 0, stream>>>(w, alpha, hebb, hidden, partial, acc5);
    k_hact<<<HDIM / HC, TB, 0, stream>>>(partial, x, i2h_w, i2h_b, h2o_w, h2v_w, h_f, h_out, acc5);
    k_hebb<<<(int)((NELEM / 4) / TB), TB, 0, stream>>>(hebb, hidden, h_f, eta, hebb_out);
    k_finish<<<1, 64, 0, stream>>>(acc5, h2o_b, h2v_b, out);
}